// Round 9
// baseline (182.481 us; speedup 1.0000x reference)
//
#include <hip/hip_runtime.h>
#include <hip/hip_bf16.h>

#define N_SOURCE   100000
#define N_TARGET   4096
#define SOURCE_DIM 512
#define EMBED_DIM  32
#define TARGET_DIM 16
#define NTILES     ((N_SOURCE + 15) / 16)   // 6250 row-tiles of 16 (exact)
#define GEMM_REPS  4                        // DIAGNOSTIC: inflate GEMM 4x

typedef __attribute__((ext_vector_type(8))) short short8;   // 8 bf16 (4 VGPR)
typedef __attribute__((ext_vector_type(4))) float f32x4;    // MFMA accumulator

static __device__ __forceinline__ ushort f2bf(float f) {
    __hip_bfloat16 h = __float2bfloat16(f);   // RNE
    return *(ushort*)&h;
}

// ---------------------------------------------------------------------------
// Kernel 0: Mt = bf16( (embed @ weight)^T )   [16][512]  (folds both GEMMs)
// ---------------------------------------------------------------------------
__global__ __launch_bounds__(256)
void k_embed_weight(const float* __restrict__ embed,   // [512][32]
                    const float* __restrict__ weight,  // [32][16]
                    ushort* __restrict__ Mt) {         // [16][512] bf16
    __shared__ float wlds[EMBED_DIM * TARGET_DIM];
    int tid = threadIdx.x;
    for (int i = tid; i < EMBED_DIM * TARGET_DIM; i += 256)
        wlds[i] = weight[i];
    __syncthreads();

    int idx = blockIdx.x * 256 + tid;                  // 0..8191
    if (idx < SOURCE_DIM * TARGET_DIM) {
        int k = idx >> 4;        // K index
        int o = idx & 15;        // output col
        float s = 0.f;
        #pragma unroll
        for (int j = 0; j < EMBED_DIM; ++j)
            s += embed[k * EMBED_DIM + j] * wlds[j * TARGET_DIM + o];
        Mt[o * SOURCE_DIM + k] = f2bf(s);              // transposed store
    }
}

// ---------------------------------------------------------------------------
// Kernel 1 (DIAGNOSTIC x4): round-8 structure exactly, but the tile-compute
// repeats GEMM_REPS times with an opaque A pointer + "memory" clobber, so
// every rep re-issues all global/LDS loads. y is overwritten with identical
// values each rep (deterministic). Purpose: lift GEMM into rocprof top-5.
// ---------------------------------------------------------------------------
__global__ __launch_bounds__(256, 4)
void k_gemm_y(const float*  __restrict__ A,      // source_feat [N_SOURCE][512]
              const float*  __restrict__ xnorm,  // [N_SOURCE]
              const ushort* __restrict__ Mt,     // [16][512] bf16
              ushort*       __restrict__ y) {    // [N_SOURCE][16] bf16
    __shared__ ushort Bl[SOURCE_DIM * TARGET_DIM];   // 16 KB, fragment-ordered
    int tid  = threadIdx.x;
    int wave = tid >> 6;
    int lane = tid & 63;
    int n    = lane & 15;     // A row within tile / B col / C col
    int g    = lane >> 4;     // k-group 0..3

    // stage B in fragment order: chunk c (16B) = fragment (kk,g,n)
    #pragma unroll
    for (int i = 0; i < 4; ++i) {
        int c  = tid + 256 * i;          // 0..1023
        int nn = c & 15;
        int kg = c >> 4;                 // kk*4+g
        int kk = kg >> 2;
        int gg = kg & 3;
        *(uint4*)&Bl[c * 8] =
            *(const uint4*)(Mt + nn * SOURCE_DIM + kk * 32 + gg * 8);
    }
    __syncthreads();

    int tile = blockIdx.x * 4 + wave;
    if (tile < NTILES) {
        int row0 = tile * 16;
        const float* Arow = A + (size_t)(row0 + n) * SOURCE_DIM + g * 8;
        const ushort* Bll = Bl + lane * 8;     // +kk*512 ushorts per step

        #pragma unroll 1
        for (int rep = 0; rep < GEMM_REPS; ++rep) {
            asm volatile("" : "+v"(Arow) :: "memory");   // force re-execution

            f32x4 acc = {0.f, 0.f, 0.f, 0.f};
            #pragma unroll
            for (int kk = 0; kk < 16; ++kk) {
                float4 a0 = *(const float4*)(Arow + kk * 32);
                float4 a1 = *(const float4*)(Arow + kk * 32 + 4);
                short8 bf = *(const short8*)(Bll + kk * 512);   // ds_read_b128
                short8 af;
                af[0] = (short)f2bf(a0.x); af[1] = (short)f2bf(a0.y);
                af[2] = (short)f2bf(a0.z); af[3] = (short)f2bf(a0.w);
                af[4] = (short)f2bf(a1.x); af[5] = (short)f2bf(a1.y);
                af[6] = (short)f2bf(a1.z); af[7] = (short)f2bf(a1.w);
                acc = __builtin_amdgcn_mfma_f32_16x16x32_bf16(af, bf, acc, 0, 0, 0);
            }

            // epilogue: lane holds C[g*4 + r][n], r = 0..3
            int m0 = g * 4;
            float4 xn = *(const float4*)(xnorm + row0 + m0);   // 16B aligned
            const float xr[4] = {xn.x, xn.y, xn.z, xn.w};
            #pragma unroll
            for (int r = 0; r < 4; ++r)
                y[(size_t)(row0 + m0 + r) * TARGET_DIM + n] = f2bf(acc[r] / xr[r]);
        }
    }
}

// ---------------------------------------------------------------------------
// Kernel 2 (exact round-6/8 version, measured 14.7 us): block per target,
// int4 index loads -> 4 independent uint4 gathers (ILP 4).
// ---------------------------------------------------------------------------
__global__ __launch_bounds__(256)
void k_gather_mean(const ushort* __restrict__ y,   // [N_SOURCE][16] bf16
                   const int*    __restrict__ src, // edge sources
                   const int*    __restrict__ rl,  // range_list [N_TARGET][2]
                   float* __restrict__ out) {      // [N_TARGET][16] f32
    int t     = blockIdx.x;
    int tid   = threadIdx.x;
    int start = rl[2 * t];
    int end   = rl[2 * t + 1];

    int slot = tid >> 1;          // 0..127
    int sub  = tid & 1;           // which 16B half of the 32B row

    float a[8];
    #pragma unroll
    for (int i = 0; i < 8; ++i) a[i] = 0.f;

    for (int base = start + slot * 4; base < end; base += 512) {
        int rem = end - base;     // >= 1 here
        int id[4];
        if (rem >= 4) {           // aligned: start%4==0 (range starts 800*t)
            int4 q = *(const int4*)(src + base);
            id[0] = q.x; id[1] = q.y; id[2] = q.z; id[3] = q.w;
        } else {
            #pragma unroll
            for (int j = 0; j < 4; ++j) id[j] = (j < rem) ? src[base + j] : 0;
        }
        #pragma unroll
        for (int j = 0; j < 4; ++j) {
            if (j < rem) {
                uint4 v = *(const uint4*)(y + (size_t)id[j] * TARGET_DIM + sub * 8);
                const uint w[4] = {v.x, v.y, v.z, v.w};
                #pragma unroll
                for (int i = 0; i < 4; ++i) {
                    uint lo = w[i] << 16;
                    uint hi = w[i] & 0xffff0000u;
                    a[2 * i]     += *(float*)&lo;
                    a[2 * i + 1] += *(float*)&hi;
                }
            }
        }
    }

    // butterfly over slot bits within the wave (lane bits 1..5)
    #pragma unroll
    for (int m = 2; m <= 32; m <<= 1) {
        #pragma unroll
        for (int i = 0; i < 8; ++i) a[i] += __shfl_xor(a[i], m);
    }

    __shared__ float red[4][16];
    int wid  = tid >> 6;
    int lane = tid & 63;
    if (lane < 2) {               // lane0 = cols 0..7, lane1 = cols 8..15
        #pragma unroll
        for (int i = 0; i < 8; ++i) red[wid][lane * 8 + i] = a[i];
    }
    __syncthreads();

    if (tid < TARGET_DIM) {
        float s = red[0][tid] + red[1][tid] + red[2][tid] + red[3][tid];
        float deg = (float)(end - start);
        deg = deg > 1.f ? deg : 1.f;
        out[t * TARGET_DIM + tid] = s / deg;
    }
}

// ---------------------------------------------------------------------------
extern "C" void kernel_launch(void* const* d_in, const int* in_sizes, int n_in,
                              void* d_out, int out_size, void* d_ws, size_t ws_size,
                              hipStream_t stream) {
    const float* source_feat = (const float*)d_in[0];  // [100000][512]
    const float* embed       = (const float*)d_in[1];  // [512][32]
    const float* weight      = (const float*)d_in[2];  // [32][16]
    const int*   edge_src    = (const int*)d_in[3];    // edge_index[0][:]
    const int*   range_list  = (const int*)d_in[4];    // [4096][2]
    const float* x_norm      = (const float*)d_in[5];  // [100000]

    float*  out = (float*)d_out;
    ushort* Mt  = (ushort*)d_ws;                        // 16 KB bf16 [16][512]
    ushort* y   = (ushort*)((char*)d_ws + 16384);       // 3.2 MB bf16

    k_embed_weight<<<32, 256, 0, stream>>>(embed, weight, Mt);

    int nblk = (NTILES + 3) / 4;                        // 1563
    k_gemm_y<<<nblk, 256, 0, stream>>>(source_feat, x_norm, Mt, y);

    k_gather_mean<<<N_TARGET, 256, 0, stream>>>(y, edge_src, range_list, out);
}

// Round 10
// 71.392 us; speedup vs baseline: 2.5560x; 2.5560x over previous
//
#include <hip/hip_runtime.h>
#include <hip/hip_bf16.h>

#define N_SOURCE   100000
#define N_TARGET   4096
#define SOURCE_DIM 512
#define EMBED_DIM  32
#define TARGET_DIM 16
#define NTILES     ((N_SOURCE + 15) / 16)   // 6250 row-tiles of 16 (exact)

typedef __attribute__((ext_vector_type(8))) short short8;   // 8 bf16 (4 VGPR)
typedef __attribute__((ext_vector_type(4))) float f32x4;    // MFMA accumulator

static __device__ __forceinline__ ushort f2bf(float f) {
    __hip_bfloat16 h = __float2bfloat16(f);   // RNE
    return *(ushort*)&h;
}

// ---------------------------------------------------------------------------
// Kernel 0: Mt = bf16( (embed @ weight)^T )   [16][512]  (folds both GEMMs)
// ---------------------------------------------------------------------------
__global__ __launch_bounds__(256)
void k_embed_weight(const float* __restrict__ embed,   // [512][32]
                    const float* __restrict__ weight,  // [32][16]
                    ushort* __restrict__ Mt) {         // [16][512] bf16
    __shared__ float wlds[EMBED_DIM * TARGET_DIM];
    int tid = threadIdx.x;
    for (int i = tid; i < EMBED_DIM * TARGET_DIM; i += 256)
        wlds[i] = weight[i];
    __syncthreads();

    int idx = blockIdx.x * 256 + tid;                  // 0..8191
    if (idx < SOURCE_DIM * TARGET_DIM) {
        int k = idx >> 4;        // K index
        int o = idx & 15;        // output col
        float s = 0.f;
        #pragma unroll
        for (int j = 0; j < EMBED_DIM; ++j)
            s += embed[k * EMBED_DIM + j] * wlds[j * TARGET_DIM + o];
        Mt[o * SOURCE_DIM + k] = f2bf(s);              // transposed store
    }
}

// ---------------------------------------------------------------------------
// Kernel 1: y = bf16( (A @ M) / xnorm ) via MFMA, B from LDS (fragment order,
// conflict-free). SINGLE CHANGE vs round 8: __launch_bounds__(256, 8) —
// round-9 diagnostic showed VALUBusy 5%, Occupancy 44% (14/32 waves/CU),
// VGPR=36: the (256,4) bound was voluntarily capping concurrency while the
// stream ran at 4.6 of 6.3 TB/s. 8 blocks/CU: LDS 8*16KB=128<=160, VGPR<=64.
// A-frag: lane holds A[lane&15][kk*32 + (lane>>4)*8 + i]
// C/D   : col = lane&15, row = (lane>>4)*4 + reg          (m89-verified)
// ---------------------------------------------------------------------------
__global__ __launch_bounds__(256, 8)
void k_gemm_y(const float*  __restrict__ A,      // source_feat [N_SOURCE][512]
              const float*  __restrict__ xnorm,  // [N_SOURCE]
              const ushort* __restrict__ Mt,     // [16][512] bf16
              ushort*       __restrict__ y) {    // [N_SOURCE][16] bf16
    __shared__ ushort Bl[SOURCE_DIM * TARGET_DIM];   // 16 KB, fragment-ordered
    int tid  = threadIdx.x;
    int wave = tid >> 6;
    int lane = tid & 63;
    int n    = lane & 15;     // A row within tile / B col / C col
    int g    = lane >> 4;     // k-group 0..3

    // stage B in fragment order: chunk c (16B) = fragment (kk,g,n)
    #pragma unroll
    for (int i = 0; i < 4; ++i) {
        int c  = tid + 256 * i;          // 0..1023
        int nn = c & 15;
        int kg = c >> 4;                 // kk*4+g
        int kk = kg >> 2;
        int gg = kg & 3;
        *(uint4*)&Bl[c * 8] =
            *(const uint4*)(Mt + nn * SOURCE_DIM + kk * 32 + gg * 8);
    }
    __syncthreads();

    int tile = blockIdx.x * 4 + wave;
    if (tile < NTILES) {
        int row0 = tile * 16;
        const float* Arow = A + (size_t)(row0 + n) * SOURCE_DIM + g * 8;
        const ushort* Bll = Bl + lane * 8;     // +kk*512 ushorts per step

        f32x4 acc = {0.f, 0.f, 0.f, 0.f};
        #pragma unroll
        for (int kk = 0; kk < 16; ++kk) {
            float4 a0 = *(const float4*)(Arow + kk * 32);
            float4 a1 = *(const float4*)(Arow + kk * 32 + 4);
            short8 bf = *(const short8*)(Bll + kk * 512);   // ds_read_b128
            short8 af;
            af[0] = (short)f2bf(a0.x); af[1] = (short)f2bf(a0.y);
            af[2] = (short)f2bf(a0.z); af[3] = (short)f2bf(a0.w);
            af[4] = (short)f2bf(a1.x); af[5] = (short)f2bf(a1.y);
            af[6] = (short)f2bf(a1.z); af[7] = (short)f2bf(a1.w);
            acc = __builtin_amdgcn_mfma_f32_16x16x32_bf16(af, bf, acc, 0, 0, 0);
        }

        // epilogue: lane holds C[g*4 + r][n], r = 0..3
        int m0 = g * 4;
        float4 xn = *(const float4*)(xnorm + row0 + m0);   // 16B aligned
        const float xr[4] = {xn.x, xn.y, xn.z, xn.w};
        #pragma unroll
        for (int r = 0; r < 4; ++r)
            y[(size_t)(row0 + m0 + r) * TARGET_DIM + n] = f2bf(acc[r] / xr[r]);
    }
}

// ---------------------------------------------------------------------------
// Kernel 2 (exact round-6/8 version, measured 14.7 us): block per target,
// int4 index loads -> 4 independent uint4 gathers (ILP 4).
// ---------------------------------------------------------------------------
__global__ __launch_bounds__(256)
void k_gather_mean(const ushort* __restrict__ y,   // [N_SOURCE][16] bf16
                   const int*    __restrict__ src, // edge sources
                   const int*    __restrict__ rl,  // range_list [N_TARGET][2]
                   float* __restrict__ out) {      // [N_TARGET][16] f32
    int t     = blockIdx.x;
    int tid   = threadIdx.x;
    int start = rl[2 * t];
    int end   = rl[2 * t + 1];

    int slot = tid >> 1;          // 0..127
    int sub  = tid & 1;           // which 16B half of the 32B row

    float a[8];
    #pragma unroll
    for (int i = 0; i < 8; ++i) a[i] = 0.f;

    for (int base = start + slot * 4; base < end; base += 512) {
        int rem = end - base;     // >= 1 here
        int id[4];
        if (rem >= 4) {           // aligned: start%4==0 (range starts 800*t)
            int4 q = *(const int4*)(src + base);
            id[0] = q.x; id[1] = q.y; id[2] = q.z; id[3] = q.w;
        } else {
            #pragma unroll
            for (int j = 0; j < 4; ++j) id[j] = (j < rem) ? src[base + j] : 0;
        }
        #pragma unroll
        for (int j = 0; j < 4; ++j) {
            if (j < rem) {
                uint4 v = *(const uint4*)(y + (size_t)id[j] * TARGET_DIM + sub * 8);
                const uint w[4] = {v.x, v.y, v.z, v.w};
                #pragma unroll
                for (int i = 0; i < 4; ++i) {
                    uint lo = w[i] << 16;
                    uint hi = w[i] & 0xffff0000u;
                    a[2 * i]     += *(float*)&lo;
                    a[2 * i + 1] += *(float*)&hi;
                }
            }
        }
    }

    // butterfly over slot bits within the wave (lane bits 1..5)
    #pragma unroll
    for (int m = 2; m <= 32; m <<= 1) {
        #pragma unroll
        for (int i = 0; i < 8; ++i) a[i] += __shfl_xor(a[i], m);
    }

    __shared__ float red[4][16];
    int wid  = tid >> 6;
    int lane = tid & 63;
    if (lane < 2) {               // lane0 = cols 0..7, lane1 = cols 8..15
        #pragma unroll
        for (int i = 0; i < 8; ++i) red[wid][lane * 8 + i] = a[i];
    }
    __syncthreads();

    if (tid < TARGET_DIM) {
        float s = red[0][tid] + red[1][tid] + red[2][tid] + red[3][tid];
        float deg = (float)(end - start);
        deg = deg > 1.f ? deg : 1.f;
        out[t * TARGET_DIM + tid] = s / deg;
    }
}

// ---------------------------------------------------------------------------
extern "C" void kernel_launch(void* const* d_in, const int* in_sizes, int n_in,
                              void* d_out, int out_size, void* d_ws, size_t ws_size,
                              hipStream_t stream) {
    const float* source_feat = (const float*)d_in[0];  // [100000][512]
    const float* embed       = (const float*)d_in[1];  // [512][32]
    const float* weight      = (const float*)d_in[2];  // [32][16]
    const int*   edge_src    = (const int*)d_in[3];    // edge_index[0][:]
    const int*   range_list  = (const int*)d_in[4];    // [4096][2]
    const float* x_norm      = (const float*)d_in[5];  // [100000]

    float*  out = (float*)d_out;
    ushort* Mt  = (ushort*)d_ws;                        // 16 KB bf16 [16][512]
    ushort* y   = (ushort*)((char*)d_ws + 16384);       // 3.2 MB bf16

    k_embed_weight<<<32, 256, 0, stream>>>(embed, weight, Mt);

    int nblk = (NTILES + 3) / 4;                        // 1563
    k_gemm_y<<<nblk, 256, 0, stream>>>(source_feat, x_norm, Mt, y);

    k_gather_mean<<<N_TARGET, 256, 0, stream>>>(y, edge_src, range_list, out);
}

// Round 11
// 64.528 us; speedup vs baseline: 2.8279x; 1.1064x over previous
//
#include <hip/hip_runtime.h>
#include <hip/hip_bf16.h>

#define N_SOURCE   100000
#define N_TARGET   4096
#define SOURCE_DIM 512
#define EMBED_DIM  32
#define TARGET_DIM 16
#define NTILES     ((N_SOURCE + 15) / 16)   // 6250 row-tiles of 16 (exact)

typedef __attribute__((ext_vector_type(8))) short short8;   // 8 bf16 (4 VGPR)
typedef __attribute__((ext_vector_type(4))) float f32x4;    // MFMA accumulator

static __device__ __forceinline__ ushort f2bf(float f) {
    __hip_bfloat16 h = __float2bfloat16(f);   // RNE
    return *(ushort*)&h;
}

// ---------------------------------------------------------------------------
// Kernel 0: Mt = bf16( (embed @ weight)^T )   [16][512]  (folds both GEMMs)
// ---------------------------------------------------------------------------
__global__ __launch_bounds__(256)
void k_embed_weight(const float* __restrict__ embed,   // [512][32]
                    const float* __restrict__ weight,  // [32][16]
                    ushort* __restrict__ Mt) {         // [16][512] bf16
    __shared__ float wlds[EMBED_DIM * TARGET_DIM];
    int tid = threadIdx.x;
    for (int i = tid; i < EMBED_DIM * TARGET_DIM; i += 256)
        wlds[i] = weight[i];
    __syncthreads();

    int idx = blockIdx.x * 256 + tid;                  // 0..8191
    if (idx < SOURCE_DIM * TARGET_DIM) {
        int k = idx >> 4;        // K index
        int o = idx & 15;        // output col
        float s = 0.f;
        #pragma unroll
        for (int j = 0; j < EMBED_DIM; ++j)
            s += embed[k * EMBED_DIM + j] * wlds[j * TARGET_DIM + o];
        Mt[o * SOURCE_DIM + k] = f2bf(s);              // transposed store
    }
}

// ---------------------------------------------------------------------------
// Kernel 1: y = bf16( (A @ M) / xnorm ) via MFMA, B from LDS (round-8 base).
// NEW: full-sector A loads + in-register lane transpose.
//   Loader map: lane = (row = lane>>2, q = lane&3); a0 = row bytes [q*16,+16)
//   of sector0, a1 of sector1 -> each instruction reads 16 rows x 64B
//   CONTIGUOUS (full 64B sectors; was 16B-used-of-64B at stride 32B ->
//   MSHR-byte-limited 4.6 TB/s per rounds 9/10).
//   Exchange to the fixed MFMA fragment map (lane(n,g) needs floats
//   kk*32+g*8..+8 = float4s F=2g,2g+1; piece p=g>>1, src lane (n<<2)|(F&3)):
//   8 __shfl pulls + 4 half-wave-uniform selects per kk. Bit-exact.
// ---------------------------------------------------------------------------
__global__ __launch_bounds__(256, 4)
void k_gemm_y(const float*  __restrict__ A,      // source_feat [N_SOURCE][512]
              const float*  __restrict__ xnorm,  // [N_SOURCE]
              const ushort* __restrict__ Mt,     // [16][512] bf16
              ushort*       __restrict__ y) {    // [N_SOURCE][16] bf16
    __shared__ ushort Bl[SOURCE_DIM * TARGET_DIM];   // 16 KB, fragment-ordered
    int tid  = threadIdx.x;
    int wave = tid >> 6;
    int lane = tid & 63;
    int n    = lane & 15;     // C col / fragment row
    int g    = lane >> 4;     // k-group 0..3

    // stage B in fragment order: chunk c (16B) = fragment (kk,g,n)
    #pragma unroll
    for (int i = 0; i < 4; ++i) {
        int c  = tid + 256 * i;          // 0..1023
        int nn = c & 15;
        int kg = c >> 4;                 // kk*4+g
        int kk = kg >> 2;
        int gg = kg & 3;
        *(uint4*)&Bl[c * 8] =
            *(const uint4*)(Mt + nn * SOURCE_DIM + kk * 32 + gg * 8);
    }
    __syncthreads();

    int tile = blockIdx.x * 4 + wave;
    if (tile < NTILES) {
        int row0 = tile * 16;

        // loader-side addressing (full-sector contiguous per instruction)
        int lr = lane >> 2;              // row this lane loads (0..15)
        int q  = lane & 3;               // 16B slot within the 64B sector
        const float* Aload = A + (size_t)(row0 + lr) * SOURCE_DIM + q * 4;

        // consumer-side exchange indices (fixed 16x4 lane transpose)
        int sA = (n << 2) | ((2 * g) & 3);       // src of float4 F=2g
        int sB = (n << 2) | ((2 * g + 1) & 3);   // src of float4 F=2g+1
        bool hi = g >= 2;                        // piece select (a0 vs a1)

        const ushort* Bll = Bl + lane * 8;       // +kk*512 ushorts per step

        f32x4 acc = {0.f, 0.f, 0.f, 0.f};
        #pragma unroll
        for (int kk = 0; kk < 16; ++kk) {
            float4 a0 = *(const float4*)(Aload + kk * 32);       // sector 0
            float4 a1 = *(const float4*)(Aload + kk * 32 + 16);  // sector 1

            // pack to bf16 dwords (dword j = floats 2j,2j+1 of the float4)
            uint u00 = (uint)f2bf(a0.x) | ((uint)f2bf(a0.y) << 16);
            uint u01 = (uint)f2bf(a0.z) | ((uint)f2bf(a0.w) << 16);
            uint u10 = (uint)f2bf(a1.x) | ((uint)f2bf(a1.y) << 16);
            uint u11 = (uint)f2bf(a1.z) | ((uint)f2bf(a1.w) << 16);

            // pull the fragment dwords from the loader lanes
            uint e0 = (uint)__shfl((int)u00, sA);
            uint e1 = (uint)__shfl((int)u01, sA);
            uint e2 = (uint)__shfl((int)u00, sB);
            uint e3 = (uint)__shfl((int)u01, sB);
            uint f0 = (uint)__shfl((int)u10, sA);
            uint f1 = (uint)__shfl((int)u11, sA);
            uint f2 = (uint)__shfl((int)u10, sB);
            uint f3 = (uint)__shfl((int)u11, sB);

            union { short8 s; uint u[4]; } af;
            af.u[0] = hi ? f0 : e0;
            af.u[1] = hi ? f1 : e1;
            af.u[2] = hi ? f2 : e2;
            af.u[3] = hi ? f3 : e3;

            short8 bf = *(const short8*)(Bll + kk * 512);   // ds_read_b128
            acc = __builtin_amdgcn_mfma_f32_16x16x32_bf16(af.s, bf, acc, 0, 0, 0);
        }

        // epilogue: lane holds C[g*4 + r][n], r = 0..3
        int m0 = g * 4;
        float4 xn = *(const float4*)(xnorm + row0 + m0);   // 16B aligned
        const float xr[4] = {xn.x, xn.y, xn.z, xn.w};
        #pragma unroll
        for (int r = 0; r < 4; ++r)
            y[(size_t)(row0 + m0 + r) * TARGET_DIM + n] = f2bf(acc[r] / xr[r]);
    }
}

// ---------------------------------------------------------------------------
// Kernel 2 (exact round-6/8 version, measured 14.7 us): block per target,
// int4 index loads -> 4 independent uint4 gathers (ILP 4).
// ---------------------------------------------------------------------------
__global__ __launch_bounds__(256)
void k_gather_mean(const ushort* __restrict__ y,   // [N_SOURCE][16] bf16
                   const int*    __restrict__ src, // edge sources
                   const int*    __restrict__ rl,  // range_list [N_TARGET][2]
                   float* __restrict__ out) {      // [N_TARGET][16] f32
    int t     = blockIdx.x;
    int tid   = threadIdx.x;
    int start = rl[2 * t];
    int end   = rl[2 * t + 1];

    int slot = tid >> 1;          // 0..127
    int sub  = tid & 1;           // which 16B half of the 32B row

    float a[8];
    #pragma unroll
    for (int i = 0; i < 8; ++i) a[i] = 0.f;

    for (int base = start + slot * 4; base < end; base += 512) {
        int rem = end - base;     // >= 1 here
        int id[4];
        if (rem >= 4) {           // aligned: start%4==0 (range starts 800*t)
            int4 qd = *(const int4*)(src + base);
            id[0] = qd.x; id[1] = qd.y; id[2] = qd.z; id[3] = qd.w;
        } else {
            #pragma unroll
            for (int j = 0; j < 4; ++j) id[j] = (j < rem) ? src[base + j] : 0;
        }
        #pragma unroll
        for (int j = 0; j < 4; ++j) {
            if (j < rem) {
                uint4 v = *(const uint4*)(y + (size_t)id[j] * TARGET_DIM + sub * 8);
                const uint w[4] = {v.x, v.y, v.z, v.w};
                #pragma unroll
                for (int i = 0; i < 4; ++i) {
                    uint lo = w[i] << 16;
                    uint hiw = w[i] & 0xffff0000u;
                    a[2 * i]     += *(float*)&lo;
                    a[2 * i + 1] += *(float*)&hiw;
                }
            }
        }
    }

    // butterfly over slot bits within the wave (lane bits 1..5)
    #pragma unroll
    for (int m = 2; m <= 32; m <<= 1) {
        #pragma unroll
        for (int i = 0; i < 8; ++i) a[i] += __shfl_xor(a[i], m);
    }

    __shared__ float red[4][16];
    int wid  = tid >> 6;
    int lane = tid & 63;
    if (lane < 2) {               // lane0 = cols 0..7, lane1 = cols 8..15
        #pragma unroll
        for (int i = 0; i < 8; ++i) red[wid][lane * 8 + i] = a[i];
    }
    __syncthreads();

    if (tid < TARGET_DIM) {
        float s = red[0][tid] + red[1][tid] + red[2][tid] + red[3][tid];
        float deg = (float)(end - start);
        deg = deg > 1.f ? deg : 1.f;
        out[t * TARGET_DIM + tid] = s / deg;
    }
}

// ---------------------------------------------------------------------------
extern "C" void kernel_launch(void* const* d_in, const int* in_sizes, int n_in,
                              void* d_out, int out_size, void* d_ws, size_t ws_size,
                              hipStream_t stream) {
    const float* source_feat = (const float*)d_in[0];  // [100000][512]
    const float* embed       = (const float*)d_in[1];  // [512][32]
    const float* weight      = (const float*)d_in[2];  // [32][16]
    const int*   edge_src    = (const int*)d_in[3];    // edge_index[0][:]
    const int*   range_list  = (const int*)d_in[4];    // [4096][2]
    const float* x_norm      = (const float*)d_in[5];  // [100000]

    float*  out = (float*)d_out;
    ushort* Mt  = (ushort*)d_ws;                        // 16 KB bf16 [16][512]
    ushort* y   = (ushort*)((char*)d_ws + 16384);       // 3.2 MB bf16

    k_embed_weight<<<32, 256, 0, stream>>>(embed, weight, Mt);

    int nblk = (NTILES + 3) / 4;                        // 1563
    k_gemm_y<<<nblk, 256, 0, stream>>>(source_feat, x_norm, Mt, y);

    k_gather_mean<<<N_TARGET, 256, 0, stream>>>(y, edge_src, range_list, out);
}